// Round 8
// baseline (276.910 us; speedup 1.0000x reference)
//
#include <hip/hip_runtime.h>
#include <math.h>

// Problem constants (fixed by reference setup_inputs)
#define NROWS 8192
#define DDIM  256
#define EPS_V 1e-7f
// sqrt(1/T): folded into the normalized bf16 data so exp(sim/T) == __expf(dot)
#define SCALE 1.1180339887498949f

// Structure: 64 panels (128 rows) x 4 j-chunks (2048 cols) = 256 blocks = 1/CU.
// 8 waves: wr in {0,1} (64-row half), wc in {0..3} (32-col quarter of 128-col tile).
// A panel half lives in REGISTERS (a[4][8] = 128 VGPR); only B goes through LDS.
// Per wave per 128-col tile: 16 ds_read_b128 vs 64 MFMA (ratio 0.25).
//
// VGPR history: rounds 4-7 all allocated at 128 VGPR and spilled a[4][8] to
// scratch (FETCH 558 MB, WRITE 86 MB). __launch_bounds__(512) alone did NOT
// lift it — the backend targets 4 waves/EU by default for 512-thr blocks.
// Fix: amdgpu_waves_per_eu(2,2) pins the allocator to 2 waves/EU -> 256-VGPR
// budget (HipKittens attn runs exactly 8w/256VGPR, so this is achievable).
#define JCHUNK 2048
#define TILE   128
#define NJT    (JCHUNK / TILE)   // 16

typedef float f32x4 __attribute__((ext_vector_type(4)));
typedef short s16x8 __attribute__((ext_vector_type(8)));

// ---------------- workspace layout ----------------
// [0        .. 4MB   )  fbf  : normalized*SCALE features bf16, row-major 8192x256
// [4MB      .. +64KB )  nd   : 8192 float2 pairs (P = positives, T = same-label sum)
// [+64KB    .. +16B  )  cnt  : block-done counter
// [+64KB+16 .. +32KB )  keys : 8192 i32, key = (spk<<3)|lab

__device__ __forceinline__ ushort f2bf(float x) {
    unsigned u = __float_as_uint(x);
    unsigned r = (u + 0x7FFFu + ((u >> 16) & 1u)) >> 16;   // RNE
    return (ushort)r;
}

// async global->LDS, 16B/lane; LDS dest is wave-uniform base (+lane*16 implicit).
__device__ __forceinline__ void gload16(const void* gptr, void* lptr) {
    __builtin_amdgcn_global_load_lds(
        (__attribute__((address_space(1))) void*)(uintptr_t)gptr,
        (__attribute__((address_space(3))) void*)(uintptr_t)lptr,
        16, 0, 0);
}

// One wave per row: normalize (*SCALE), convert to bf16, emit packed key.
// Also zero-initializes nd pairs and the done-counter.
__global__ void normbf_kernel(const float* __restrict__ feat,
                              const int*   __restrict__ lab,
                              const int*   __restrict__ spk,
                              ushort* __restrict__ fbf,
                              float*  __restrict__ ndf,
                              int*    __restrict__ cnt,
                              int*    __restrict__ keys) {
    const int gt = blockIdx.x * blockDim.x + threadIdx.x;
    if (gt < 2 * NROWS) ndf[gt] = 0.0f;
    if (gt == 2 * NROWS) *cnt = 0;
    const int row  = gt >> 6;
    const int lane = gt & 63;
    const float4 v = reinterpret_cast<const float4*>(feat + (size_t)row * DDIM)[lane];
    float ss = v.x * v.x + v.y * v.y + v.z * v.z + v.w * v.w;
    #pragma unroll
    for (int m = 32; m; m >>= 1) ss += __shfl_xor(ss, m);
    const float inv = SCALE / fmaxf(sqrtf(ss), 1e-12f);
    ushort4 o;
    o.x = f2bf(v.x * inv);
    o.y = f2bf(v.y * inv);
    o.z = f2bf(v.z * inv);
    o.w = f2bf(v.w * inv);
    reinterpret_cast<ushort4*>(fbf + (size_t)row * DDIM)[lane] = o;
    if (lane == 0) keys[row] = (spk[row] << 3) | lab[row];
}

__global__ __launch_bounds__(512)
__attribute__((amdgpu_waves_per_eu(2, 2)))
void main_kernel(
        const ushort* __restrict__ fbf,
        const int*    __restrict__ keys,
        float2*       __restrict__ nd,
        int*          __restrict__ cnt,
        float*        __restrict__ out) {
    __shared__ __align__(16) ushort Bs[2][TILE * DDIM];   // 2 x 64 KB
    __shared__ int s_last;

    const int tid  = threadIdx.x;
    const int lane = tid & 63;
    const int wid  = tid >> 6;      // 0..7
    const int wr   = wid >> 2;      // 0..1  (64-row half of panel)
    const int wc   = wid & 3;       // 0..3  (32-col quarter of 128-col tile)
    const int g    = lane >> 4;     // 0..3
    const int ln   = lane & 15;

    const int panel = blockIdx.x & 63;
    const int jc    = blockIdx.x >> 6;
    const int p0    = panel * 128;
    const int jbase = jc * JCHUNK;
    // diagonal j-tile index within this chunk (or -1)
    const int diag_jt = (jc == (p0 >> 11)) ? ((p0 & 2047) >> 7) : -1;

    // staging decomposition: lane -> (rsub = lane>>5 row, cphys = lane&31 chunk)
    // stored data at phys chunk p holds logical chunk p ^ (row&7) (involution)
    const int rsub  = lane >> 5;
    const int cphys = lane & 31;

    // ---- prologue: stage B tile 0; A-half into registers from global (L2-hot) ----
    #pragma unroll
    for (int q = 0; q < 8; ++q) {
        const int r0  = wid * 16 + q * 2;
        const int row = r0 + rsub;
        const int cl  = cphys ^ (row & 7);
        gload16(fbf + (size_t)(jbase + row) * DDIM + cl * 8, &Bs[0][r0 * DDIM]);
    }

    s16x8 a[4][8];                   // 64 rows x K=256 -> 128 VGPR, stays in regs
    #pragma unroll
    for (int fi = 0; fi < 4; ++fi) {
        const ushort* arow = fbf + (size_t)(p0 + wr * 64 + fi * 16 + ln) * DDIM;
        #pragma unroll
        for (int kf = 0; kf < 8; ++kf)
            a[fi][kf] = *reinterpret_cast<const s16x8*>(arow + kf * 32 + g * 8);
    }
    int ki[16];
    #pragma unroll
    for (int t = 0; t < 16; ++t)
        ki[t] = keys[p0 + wr * 64 + (t >> 2) * 16 + g * 4 + (t & 3)];

    float T[16], P[16];
    #pragma unroll
    for (int t = 0; t < 16; ++t) { T[t] = 0.0f; P[t] = 0.0f; }

    __syncthreads();

    for (int jt = 0; jt < NJT; ++jt) {
        const int cur = jt & 1;
        if (jt + 1 < NJT) {          // prefetch next B tile
            const int j0n = jbase + (jt + 1) * TILE;
            #pragma unroll
            for (int q = 0; q < 8; ++q) {
                const int r0  = wid * 16 + q * 2;
                const int row = r0 + rsub;
                const int cl  = cphys ^ (row & 7);
                gload16(fbf + (size_t)(j0n + row) * DDIM + cl * 8, &Bs[cur ^ 1][r0 * DDIM]);
            }
        }
        const int j0  = jbase + jt * TILE;
        const int kj0 = keys[j0 + wc * 32 + ln];        // issued early
        const int kj1 = keys[j0 + wc * 32 + 16 + ln];
        const ushort* B = Bs[cur];

        f32x4 acc[4][2];
        #pragma unroll
        for (int fi = 0; fi < 4; ++fi)
            #pragma unroll
            for (int fj = 0; fj < 2; ++fj)
                #pragma unroll
                for (int k = 0; k < 4; ++k) acc[fi][fj][k] = 0.0f;

        #pragma unroll
        for (int kf = 0; kf < 8; ++kf) {
            const int ch = ((kf * 4 + g) ^ (ln & 7)) * 8;
            const s16x8 b0 = *reinterpret_cast<const s16x8*>(&B[(wc * 32 + ln) * DDIM + ch]);
            const s16x8 b1 = *reinterpret_cast<const s16x8*>(&B[(wc * 32 + 16 + ln) * DDIM + ch]);
            #pragma unroll
            for (int fi = 0; fi < 4; ++fi) {
                acc[fi][0] = __builtin_amdgcn_mfma_f32_16x16x32_bf16(a[fi][kf], b0, acc[fi][0], 0, 0, 0);
                acc[fi][1] = __builtin_amdgcn_mfma_f32_16x16x32_bf16(a[fi][kf], b1, acc[fi][1], 0, 0, 0);
            }
        }

        // epilogue: C/D layout col = ln, row = g*4 + r (+fi*16 + wr*64)
        if (jt != diag_jt) {
            #pragma unroll
            for (int fj = 0; fj < 2; ++fj) {
                const int kj = fj ? kj1 : kj0;
                #pragma unroll
                for (int fi = 0; fi < 4; ++fi)
                    #pragma unroll
                    for (int r = 0; r < 4; ++r) {
                        const int t  = fi * 4 + r;
                        const float e = __expf(acc[fi][fj][r]);
                        const int  kd = ki[t] ^ kj;
                        T[t] += ((kd & 7) == 0) ? e : 0.0f;
                        P[t] += (kd == 0) ? e : 0.0f;
                    }
            }
        } else {
            #pragma unroll
            for (int fj = 0; fj < 2; ++fj) {
                const int kj = fj ? kj1 : kj0;
                const int gj = j0 + wc * 32 + fj * 16 + ln;
                #pragma unroll
                for (int fi = 0; fi < 4; ++fi)
                    #pragma unroll
                    for (int r = 0; r < 4; ++r) {
                        const int t  = fi * 4 + r;
                        const int gi = p0 + wr * 64 + fi * 16 + g * 4 + r;
                        const float e = __expf(acc[fi][fj][r]);
                        const int  kd = ki[t] ^ kj;
                        const bool ns = (gi != gj);
                        T[t] += (((kd & 7) == 0) && ns) ? e : 0.0f;
                        P[t] += ((kd == 0) && ns) ? e : 0.0f;
                    }
            }
        }
        __syncthreads();   // drains prefetch (vmcnt) + WAR-protects Bs[cur]
    }

    // Reduce over the 16 column-lanes, then one atomic pair per (row, wave).
    #pragma unroll
    for (int t = 0; t < 16; ++t) {
        float pv = P[t], tv = T[t];
        #pragma unroll
        for (int m = 1; m < 16; m <<= 1) {
            pv += __shfl_xor(pv, m);
            tv += __shfl_xor(tv, m);
        }
        if (ln == 0) {
            const int gi = p0 + wr * 64 + (t >> 2) * 16 + g * 4 + (t & 3);
            atomicAdd(&nd[gi].x, pv);
            atomicAdd(&nd[gi].y, tv);
        }
    }

    // ---- last-block final reduction (device-scope counter pattern) ----
    __syncthreads();
    if (tid == 0) {
        __threadfence();
        s_last = (atomicAdd(cnt, 1) == (int)gridDim.x - 1) ? 1 : 0;
    }
    __syncthreads();
    if (s_last) {
        __threadfence();
        float tot = 0.0f;
        int   c   = 0;
        for (int i = tid; i < NROWS; i += 512) {
            const float2 v = nd[i];
            if (v.x > 0.0f) {                    // valid <=> some positive exists
                tot += logf(v.y + EPS_V) - logf(v.x);
                c   += 1;
            }
        }
        float* st = reinterpret_cast<float*>(&Bs[0][0]);
        int*   sc = reinterpret_cast<int*>(&Bs[1][0]);
        st[tid] = tot;
        sc[tid] = c;
        __syncthreads();
        for (int s = 256; s > 0; s >>= 1) {
            if (tid < s) { st[tid] += st[tid + s]; sc[tid] += sc[tid + s]; }
            __syncthreads();
        }
        if (tid == 0) out[0] = (sc[0] > 0) ? (st[0] / (float)sc[0]) : 0.0f;
    }
}

extern "C" void kernel_launch(void* const* d_in, const int* in_sizes, int n_in,
                              void* d_out, int out_size, void* d_ws, size_t ws_size,
                              hipStream_t stream) {
    const float* feat = (const float*)d_in[0];
    const int*   lab  = (const int*)d_in[1];
    const int*   spk  = (const int*)d_in[2];

    ushort* fbf  = (ushort*)d_ws;
    char*   base = (char*)d_ws + (size_t)NROWS * DDIM * sizeof(ushort);
    float2* nd   = (float2*)base;
    int*    cnt  = (int*)(base + 2 * NROWS * sizeof(float));
    int*    keys = (int*)(base + 2 * NROWS * sizeof(float) + 16);
    float*  outp = (float*)d_out;

    normbf_kernel<<<(NROWS * 64) / 256, 256, 0, stream>>>(feat, lab, spk, fbf,
                                                          (float*)nd, cnt, keys);
    main_kernel<<<256, 512, 0, stream>>>(fbf, keys, nd, cnt, outp);
}

// Round 10
// 174.421 us; speedup vs baseline: 1.5876x; 1.5876x over previous
//
#include <hip/hip_runtime.h>
#include <math.h>

// Problem constants (fixed by reference setup_inputs)
#define NROWS 8192
#define DDIM  256
#define EPS_V 1e-7f
// sqrt(1/T) folded into normalized bf16 data so exp(sim/T) == __expf(dot)
#define SCALE 1.1180339887498949f

// Grid: 32 i-panels (256 rows) x 8 j-chunks (1024 cols) = 256 blocks = 1/CU.
// Block: 512 thr = 8 waves; wr = wid>>1 (0..3, 64-row slice), wc = wid&1
// (0..1, 128-col half of the 256-col j-tile). Wave owns 64x128 output:
// acc[4][8] f32x4 = 128 regs -> MFMA C/D class (AGPRs on gfx950 unified RF).
// Persistent arch state per thread: T[16]+P[16]+ki[16] + transients ~= 120
// arch VGPRs -> fits the 128-VGPR allocation the backend insists on
// (rounds 4-8: every attempt to exceed 128 arch VGPRs spilled to scratch).
// Per BK=64 step per wave: 8 A + 16 B ds_read_b128 vs 64 MFMA -> LDS ~31%
// of MFMA cycles (m201-balanced). j-sweep: 4 tiles x 4 BK-steps = 16 steps.

typedef float f32x4 __attribute__((ext_vector_type(4)));
typedef short s16x8 __attribute__((ext_vector_type(8)));

// ---------------- workspace layout ----------------
// [0        .. 4MB   )  fbf  : normalized*SCALE features bf16, row-major 8192x256
// [4MB      .. +64KB )  nd   : 8192 float2 (P = positives, T = same-label sum)
// [+64KB    .. +16B  )  cnt  : block-done counter
// [+64KB+16 .. +32KB )  keys : 8192 i32, key = (spk<<3)|lab

__device__ __forceinline__ ushort f2bf(float x) {
    unsigned u = __float_as_uint(x);
    unsigned r = (u + 0x7FFFu + ((u >> 16) & 1u)) >> 16;   // RNE
    return (ushort)r;
}

// async global->LDS, 16B/lane; LDS dest is wave-uniform base (+lane*16 implicit).
__device__ __forceinline__ void gload16(const void* gptr, void* lptr) {
    __builtin_amdgcn_global_load_lds(
        (__attribute__((address_space(1))) void*)(uintptr_t)gptr,
        (__attribute__((address_space(3))) void*)(uintptr_t)lptr,
        16, 0, 0);
}

// One wave per row: normalize (*SCALE), convert to bf16, emit packed key.
// Also zero-initializes nd pairs and the done-counter.
__global__ void normbf_kernel(const float* __restrict__ feat,
                              const int*   __restrict__ lab,
                              const int*   __restrict__ spk,
                              ushort* __restrict__ fbf,
                              float*  __restrict__ ndf,
                              int*    __restrict__ cnt,
                              int*    __restrict__ keys) {
    const int gt = blockIdx.x * blockDim.x + threadIdx.x;
    if (gt < 2 * NROWS) ndf[gt] = 0.0f;
    if (gt == 2 * NROWS) *cnt = 0;
    const int row  = gt >> 6;
    const int lane = gt & 63;
    const float4 v = reinterpret_cast<const float4*>(feat + (size_t)row * DDIM)[lane];
    float ss = v.x * v.x + v.y * v.y + v.z * v.z + v.w * v.w;
    #pragma unroll
    for (int m = 32; m; m >>= 1) ss += __shfl_xor(ss, m);
    const float inv = SCALE / fmaxf(sqrtf(ss), 1e-12f);
    ushort4 o;
    o.x = f2bf(v.x * inv);
    o.y = f2bf(v.y * inv);
    o.z = f2bf(v.z * inv);
    o.w = f2bf(v.w * inv);
    reinterpret_cast<ushort4*>(fbf + (size_t)row * DDIM)[lane] = o;
    if (lane == 0) keys[row] = (spk[row] << 3) | lab[row];
}

__global__ __launch_bounds__(512) void main_kernel(
        const ushort* __restrict__ fbf,
        const int*    __restrict__ keys,
        float2*       __restrict__ nd,
        int*          __restrict__ cnt,
        float*        __restrict__ out) {
    // A,B tiles: 256 rows x BK=64 bf16, double-buffered = 4 x 32 KB = 128 KB.
    __shared__ __align__(16) ushort Asm[2][256 * 64];
    __shared__ __align__(16) ushort Bsm[2][256 * 64];
    __shared__ int s_last;

    const int tid  = threadIdx.x;
    const int lane = tid & 63;
    const int wid  = tid >> 6;      // 0..7
    const int wr   = wid >> 1;      // 0..3  (64-row slice of 256-row panel)
    const int wc   = wid & 1;       // 0..1  (128-col half of 256-col j-tile)
    const int g    = lane >> 4;     // 0..3
    const int ln   = lane & 15;

    const int ip    = blockIdx.x & 31;
    const int jc    = blockIdx.x >> 5;
    const int p0    = ip * 256;
    const int jbase = jc * 1024;

    // staging: one gload16 wave-instr writes 1024 B = 8 rows x 128 B (BK row).
    // lane -> (rsub = lane>>3 row-in-group, cphys = lane&7 chunk). Stored data
    // at phys chunk p holds logical chunk p ^ (row&7); r0 % 8 == 0 so
    // row&7 == rsub. Same XOR applied on reads (involution).
    const int rsub = lane >> 3;
    const int clog = (lane & 7) ^ rsub;

    // ---- prologue: stage step 0 (jt=0, kc=0) into buffer 0 ----
    #pragma unroll
    for (int q = 0; q < 4; ++q) {
        const int r0  = wid * 32 + q * 8;
        const int row = r0 + rsub;
        gload16(fbf + (size_t)(p0 + row) * DDIM + clog * 8, &Asm[0][r0 * 64]);
        gload16(fbf + (size_t)(jbase + row) * DDIM + clog * 8, &Bsm[0][r0 * 64]);
    }

    int ki[16];
    #pragma unroll
    for (int t = 0; t < 16; ++t)
        ki[t] = keys[p0 + wr * 64 + (t >> 2) * 16 + g * 4 + (t & 3)];

    float T[16], P[16];
    #pragma unroll
    for (int t = 0; t < 16; ++t) { T[t] = 0.0f; P[t] = 0.0f; }

    __syncthreads();

    f32x4 acc[4][8];

    for (int jt = 0; jt < 4; ++jt) {
        const int j0 = jbase + jt * 256;
        const bool diag = (j0 == p0);      // self-pairs live in this j-tile

        #pragma unroll
        for (int kc = 0; kc < 4; ++kc) {
            const int step = jt * 4 + kc;
            const int cur  = step & 1;

            // stage next step's tiles into the other buffer
            if (step + 1 < 16) {
                const int jn = (step + 1) >> 2;
                const int kn = (step + 1) & 3;
                #pragma unroll
                for (int q = 0; q < 4; ++q) {
                    const int r0  = wid * 32 + q * 8;
                    const int row = r0 + rsub;
                    gload16(fbf + (size_t)(p0 + row) * DDIM + kn * 64 + clog * 8,
                            &Asm[cur ^ 1][r0 * 64]);
                    gload16(fbf + (size_t)(jbase + jn * 256 + row) * DDIM + kn * 64 + clog * 8,
                            &Bsm[cur ^ 1][r0 * 64]);
                }
            }

            if (kc == 0) {
                #pragma unroll
                for (int fi = 0; fi < 4; ++fi)
                    #pragma unroll
                    for (int fj = 0; fj < 8; ++fj)
                        #pragma unroll
                        for (int k = 0; k < 4; ++k) acc[fi][fj][k] = 0.0f;
            }

            int kj[8];
            if (kc == 3) {                 // issue early; used after the MFMAs
                #pragma unroll
                for (int fj = 0; fj < 8; ++fj)
                    kj[fj] = keys[j0 + wc * 128 + fj * 16 + ln];
            }

            const ushort* A = Asm[cur];
            const ushort* B = Bsm[cur];
            #pragma unroll
            for (int ks = 0; ks < 2; ++ks) {
                const int ch = ((ks * 4 + g) ^ (ln & 7)) * 8;
                s16x8 a[4], b[8];
                #pragma unroll
                for (int fi = 0; fi < 4; ++fi)
                    a[fi] = *reinterpret_cast<const s16x8*>(
                        &A[(wr * 64 + fi * 16 + ln) * 64 + ch]);
                #pragma unroll
                for (int fj = 0; fj < 8; ++fj)
                    b[fj] = *reinterpret_cast<const s16x8*>(
                        &B[(wc * 128 + fj * 16 + ln) * 64 + ch]);
                __builtin_amdgcn_s_setprio(1);
                #pragma unroll
                for (int fi = 0; fi < 4; ++fi)
                    #pragma unroll
                    for (int fj = 0; fj < 8; ++fj)
                        acc[fi][fj] = __builtin_amdgcn_mfma_f32_16x16x32_bf16(
                            a[fi], b[fj], acc[fi][fj], 0, 0, 0);
                __builtin_amdgcn_s_setprio(0);
            }

            if (kc == 3) {
                // epilogue: C/D layout col = ln, row = g*4 + r (+fi*16 + wr*64)
                if (!diag) {
                    #pragma unroll
                    for (int fj = 0; fj < 8; ++fj)
                        #pragma unroll
                        for (int fi = 0; fi < 4; ++fi)
                            #pragma unroll
                            for (int r = 0; r < 4; ++r) {
                                const int t  = fi * 4 + r;
                                const float e = __expf(acc[fi][fj][r]);
                                const int  kd = ki[t] ^ kj[fj];
                                T[t] += ((kd & 7) == 0) ? e : 0.0f;
                                P[t] += (kd == 0) ? e : 0.0f;
                            }
                } else {
                    #pragma unroll
                    for (int fj = 0; fj < 8; ++fj) {
                        const int gj = j0 + wc * 128 + fj * 16 + ln;
                        #pragma unroll
                        for (int fi = 0; fi < 4; ++fi)
                            #pragma unroll
                            for (int r = 0; r < 4; ++r) {
                                const int t  = fi * 4 + r;
                                const int gi = p0 + wr * 64 + fi * 16 + g * 4 + r;
                                const float e = __expf(acc[fi][fj][r]);
                                const int  kd = ki[t] ^ kj[fj];
                                const bool ns = (gi != gj);
                                T[t] += (((kd & 7) == 0) && ns) ? e : 0.0f;
                                P[t] += ((kd == 0) && ns) ? e : 0.0f;
                            }
                    }
                }
            }
            __syncthreads();   // drains stage (vmcnt) + WAR-protects buffers
        }
    }

    // Reduce over the 16 column-lanes, then one atomic pair per (row, wave).
    #pragma unroll
    for (int t = 0; t < 16; ++t) {
        float pv = P[t], tv = T[t];
        #pragma unroll
        for (int m = 1; m < 16; m <<= 1) {
            pv += __shfl_xor(pv, m);
            tv += __shfl_xor(tv, m);
        }
        if (ln == 0) {
            const int gi = p0 + wr * 64 + (t >> 2) * 16 + g * 4 + (t & 3);
            atomicAdd(&nd[gi].x, pv);
            atomicAdd(&nd[gi].y, tv);
        }
    }

    // ---- last-block final reduction (device-scope counter pattern) ----
    __syncthreads();
    if (tid == 0) {
        __threadfence();
        s_last = (atomicAdd(cnt, 1) == (int)gridDim.x - 1) ? 1 : 0;
    }
    __syncthreads();
    if (s_last) {
        __threadfence();
        float tot = 0.0f;
        int   c   = 0;
        for (int i = tid; i < NROWS; i += 512) {
            const float2 v = nd[i];
            if (v.x > 0.0f) {                    // valid <=> some positive exists
                tot += logf(v.y + EPS_V) - logf(v.x);
                c   += 1;
            }
        }
        float* st = reinterpret_cast<float*>(&Asm[0][0]);
        int*   sc = reinterpret_cast<int*>(&Bsm[0][0]);
        st[tid] = tot;
        sc[tid] = c;
        __syncthreads();
        for (int s = 256; s > 0; s >>= 1) {
            if (tid < s) { st[tid] += st[tid + s]; sc[tid] += sc[tid + s]; }
            __syncthreads();
        }
        if (tid == 0) out[0] = (sc[0] > 0) ? (st[0] / (float)sc[0]) : 0.0f;
    }
}

extern "C" void kernel_launch(void* const* d_in, const int* in_sizes, int n_in,
                              void* d_out, int out_size, void* d_ws, size_t ws_size,
                              hipStream_t stream) {
    const float* feat = (const float*)d_in[0];
    const int*   lab  = (const int*)d_in[1];
    const int*   spk  = (const int*)d_in[2];

    ushort* fbf  = (ushort*)d_ws;
    char*   base = (char*)d_ws + (size_t)NROWS * DDIM * sizeof(ushort);
    float2* nd   = (float2*)base;
    int*    cnt  = (int*)(base + 2 * NROWS * sizeof(float));
    int*    keys = (int*)(base + 2 * NROWS * sizeof(float) + 16);
    float*  outp = (float*)d_out;

    normbf_kernel<<<(NROWS * 64) / 256, 256, 0, stream>>>(feat, lab, spk, fbf,
                                                          (float*)nd, cnt, keys);
    main_kernel<<<256, 512, 0, stream>>>(fbf, keys, nd, cnt, outp);
}